// Round 1
// baseline (67.048 us; speedup 1.0000x reference)
//
#include <hip/hip_runtime.h>

// Problem constants (from reference setup_inputs)
constexpr int B_ = 4;
constexpr int N_ = 4096;
constexpr int C_ = 256;
constexpr int S_ = 8;
constexpr int Q_ = 256;
constexpr int SIZE_ = 64;          // sqrt(N)
constexpr float EPS_ = 1e-4f;
constexpr int NQ_ = B_ * S_ * Q_;  // 8192 total query points

// One wave (64 lanes) per query point; each lane covers 4 channels (float4).
// Weights: mask[n] = relu(1 - (|py-y| + |px-x|) + eps)^2, nonzero only within
// a 4x4 lattice window around (floor(py), floor(px)). Normalize by (sum+eps).
__global__ __launch_bounds__(256) void sqe_kernel(
    const float* __restrict__ features,   // (B, N, C)
    const float* __restrict__ qp,         // (B, S, Q, 2)
    float* __restrict__ out)              // (B, S, Q, C)
{
    const int wave = threadIdx.x >> 6;            // 0..3
    const int lane = threadIdx.x & 63;            // 0..63
    const int g = blockIdx.x * 4 + wave;          // global query id
    if (g >= NQ_) return;

    const int b = g / (S_ * Q_);

    const float py = qp[g * 2 + 0];
    const float px = qp[g * 2 + 1];
    const int fy = (int)floorf(py);
    const int fx = (int)floorf(px);

    // 4x4 candidate window: covers every lattice point with L1 dist < 1+eps
    float w[16];
    float wsum = 0.0f;
#pragma unroll
    for (int i = 0; i < 4; ++i) {
        const int y = fy - 1 + i;
        const float dy = fabsf(py - (float)y);
#pragma unroll
        for (int j = 0; j < 4; ++j) {
            const int x = fx - 1 + j;
            const float dx = fabsf(px - (float)x);
            float t = 1.0f - (dy + dx) + EPS_;
            t = fmaxf(t, 0.0f);
            float ww = t * t;
            const bool inb = (y >= 0) && (y < SIZE_) && (x >= 0) && (x < SIZE_);
            ww = inb ? ww : 0.0f;
            w[i * 4 + j] = ww;
            wsum += ww;
        }
    }
    const float inv = 1.0f / (wsum + EPS_);

    const float4* frow = (const float4*)(features + (size_t)b * N_ * C_);
    float4 acc = make_float4(0.f, 0.f, 0.f, 0.f);
#pragma unroll
    for (int i = 0; i < 4; ++i) {
        const int y = fy - 1 + i;
#pragma unroll
        for (int j = 0; j < 4; ++j) {
            const float ww = w[i * 4 + j];
            if (ww > 0.0f) {                      // wave-uniform branch
                const int x = fx - 1 + j;
                const int n = y * SIZE_ + x;
                const float4 f = frow[(size_t)n * (C_ / 4) + lane];
                acc.x += ww * f.x;
                acc.y += ww * f.y;
                acc.z += ww * f.z;
                acc.w += ww * f.w;
            }
        }
    }

    float4* o = (float4*)(out + (size_t)g * C_);
    o[lane] = make_float4(acc.x * inv, acc.y * inv, acc.z * inv, acc.w * inv);
}

extern "C" void kernel_launch(void* const* d_in, const int* in_sizes, int n_in,
                              void* d_out, int out_size, void* d_ws, size_t ws_size,
                              hipStream_t stream) {
    const float* features = (const float*)d_in[0];
    const float* qp       = (const float*)d_in[1];
    float* out            = (float*)d_out;

    const int blocks = (NQ_ + 3) / 4;   // 4 queries (waves) per 256-thread block
    sqe_kernel<<<blocks, 256, 0, stream>>>(features, qp, out);
}